// Round 8
// baseline (572.478 us; speedup 1.0000x reference)
//
#include <hip/hip_runtime.h>
#include <hip/hip_bf16.h>

#define B_SZ 16384
#define D_SZ 1024
#define H_SZ 2048
#define C_SZ 128
#define T_STEPS 20

typedef __attribute__((ext_vector_type(4))) float f32x4;
typedef __attribute__((ext_vector_type(8))) short bf16x8;

__device__ __forceinline__ unsigned int lif_mask(float i1) {
    float u = 0.0f;
    unsigned int m = 0;
    #pragma unroll
    for (int t = 0; t < T_STEPS; ++t) {
        u = __fadd_rn(__fmul_rn(0.9f, u), i1);   // match np: separate mul, add
        if (u >= 1.0f) { m |= (1u << t); u = 0.0f; }
    }
    return m;
}

// ---------------- generic fp32 -> 2 bf16 planes splitter (RNE hi, RNE mid) ----------
__global__ void k_split2(const float* __restrict__ src, unsigned short* __restrict__ dst, int n) {
    int i = blockIdx.x * blockDim.x + threadIdx.x;   // float4 index
    float4 v = reinterpret_cast<const float4*>(src)[i];
    float f[4] = {v.x, v.y, v.z, v.w};
    unsigned short h[4], m[4];
    #pragma unroll
    for (int j = 0; j < 4; ++j) {
        __hip_bfloat16 hb = __float2bfloat16(f[j]);
        h[j] = __bfloat16_as_ushort(hb);
        m[j] = __bfloat16_as_ushort(__float2bfloat16(f[j] - __bfloat162float(hb)));
    }
    reinterpret_cast<ushort4*>(dst)[i] = make_ushort4(h[0], h[1], h[2], h[3]);
    reinterpret_cast<ushort4*>(dst + n)[i] = make_ushort4(m[0], m[1], m[2], m[3]);
}

// ---------------- pre-permute W2 planes into MFMA fragment order (K2) ----------------
// dst u16 layout: [kt(64)][ch(2)][s(2)][nt(4)][lane(64)][8]
__global__ void k_w2frag(const unsigned short* __restrict__ W2p, unsigned short* __restrict__ W2f) {
    int idx = blockIdx.x * blockDim.x + threadIdx.x;   // 0..65535
    int lane = idx & 63;
    int nt   = (idx >> 6) & 3;
    int s    = (idx >> 8) & 1;
    int ch   = (idx >> 9) & 1;
    int kt   = idx >> 10;
    int c = ch * 64 + nt * 16 + (lane & 15);
    int h = kt * 32 + (lane >> 4) * 8;
    uint4 v = *reinterpret_cast<const uint4*>(W2p + ((size_t)s * C_SZ + c) * H_SZ + h);
    *reinterpret_cast<uint4*>(W2f + (size_t)idx * 8) = v;
}

// ---------------- pre-permute W1 planes into MFMA fragment order (K1) ----------------
// dst u16 layout: [p(16)][kt(32)][s(2)][m(8)][lane(64)][8]
// value = w1s[s][h = p*128 + m*16 + (lane&15)][k = kt*32 + (lane>>4)*8 .. +7]
__global__ void k_w1frag(const unsigned short* __restrict__ w1s, unsigned short* __restrict__ w1f) {
    int idx = blockIdx.x * blockDim.x + threadIdx.x;   // 0..524287
    int lane = idx & 63;
    int m    = (idx >> 6) & 7;
    int s    = (idx >> 9) & 1;
    int kt   = (idx >> 10) & 31;
    int p    = idx >> 15;
    int h = p * 128 + m * 16 + (lane & 15);
    int k = kt * 32 + (lane >> 4) * 8;
    uint4 v = *reinterpret_cast<const uint4*>(w1s + ((size_t)s * H_SZ + h) * D_SZ + k);
    *reinterpret_cast<uint4*>(w1f + (size_t)idx * 8) = v;
}

// ---------------- fused split + frag-permute of x -----------------------------------
// dst u16 layout: [bg(256)][kt(32)][s(2)][nt(4)][lane(64)][8]
// value = splitplane_s( x[b = bg*64 + nt*16 + (lane&15)][k = kt*32 + (lane>>4)*8 .. +7] )
__global__ void k_xfrag(const float* __restrict__ x, unsigned short* __restrict__ xf) {
    int idx = blockIdx.x * blockDim.x + threadIdx.x;   // 0..2097151
    int lane = idx & 63;
    int nt   = (idx >> 6) & 3;
    int kt   = (idx >> 8) & 31;
    int bg   = idx >> 13;
    int b = bg * 64 + nt * 16 + (lane & 15);
    int k = kt * 32 + (lane >> 4) * 8;
    const float* src = x + (size_t)b * D_SZ + k;
    float4 v0 = *reinterpret_cast<const float4*>(src);
    float4 v1 = *reinterpret_cast<const float4*>(src + 4);
    float f[8] = {v0.x, v0.y, v0.z, v0.w, v1.x, v1.y, v1.z, v1.w};
    unsigned short h[8], m[8];
    #pragma unroll
    for (int j = 0; j < 8; ++j) {
        __hip_bfloat16 hb = __float2bfloat16(f[j]);
        h[j] = __bfloat16_as_ushort(hb);
        m[j] = __bfloat16_as_ushort(__float2bfloat16(f[j] - __bfloat162float(hb)));
    }
    size_t base = (((size_t)(bg * 32 + kt) * 8) + nt) * 512 + (size_t)lane * 8;
    *reinterpret_cast<ushort4*>(xf + base)         = make_ushort4(h[0], h[1], h[2], h[3]);
    *reinterpret_cast<ushort4*>(xf + base + 4)     = make_ushort4(h[4], h[5], h[6], h[7]);
    *reinterpret_cast<ushort4*>(xf + base + 2048)  = make_ushort4(m[0], m[1], m[2], m[3]);
    *reinterpret_cast<ushort4*>(xf + base + 2052)  = make_ushort4(m[4], m[5], m[6], m[7]);
}

// ---------------- K1: LDS-free, barrier-free frag-GEMM + fused LIF -------------------
// Grid 2048 blocks x 256 thr (4 waves, 64x64 out each). A = W1 frags (w1f),
// B = x frags (xf) — ALL hot-loop loads are contiguous 1024 B wave-loads.
// XCD swizzle: each XCD owns 16 b-panels; 4x4 sub-chunks of (b_panel, h_idx).
// launch_bounds(256,2): VGPR cap 256 — room for acc(64)+frags(64)+pipeline, no spill.
__global__ __launch_bounds__(256, 2) void k_gemm1_frag(
    const unsigned short* __restrict__ xf,    // fragment-ordered x planes
    const unsigned short* __restrict__ w1f,   // fragment-ordered W1 planes
    const float* __restrict__ b1,
    unsigned short* __restrict__ M16,
    unsigned char* __restrict__ M4,
    unsigned int* __restrict__ spike_count)
{
    const int tid  = threadIdx.x;
    const int wv   = tid >> 6;
    const int lane = tid & 63;
    const int l15  = lane & 15;
    const int g    = lane >> 4;
    const int wr   = wv >> 1;
    const int wc   = wv & 1;

    const int wg    = blockIdx.x;
    const int xcd   = wg & 7;
    const int local = wg >> 3;
    const int sc    = local >> 4;
    const int sl    = local & 15;
    const int b_panel = xcd * 16 + (sc >> 2) * 4 + (sl >> 2);
    const int h_idx   = (sc & 3) * 4 + (sl & 3);
    const int hb0 = h_idx * 128;
    const int bb0 = b_panel * 128;

    f32x4 acc[4][4];
    #pragma unroll
    for (int i = 0; i < 4; ++i)
        #pragma unroll
        for (int j = 0; j < 4; ++j)
            acc[i][j] = (f32x4){0.f, 0.f, 0.f, 0.f};

    // A: [p][kt][s][m][lane*8]; strides (u16): m 512, s 4096, kt 8192, p 262144
    const unsigned short* Ab = w1f + (size_t)h_idx * 262144 + (size_t)wr * 2048 + (size_t)lane * 8;
    // B: [bg][kt][s][nt][lane*8]; strides (u16): nt 512, s 2048, kt 4096, bg 131072
    const unsigned short* Bb = xf + (size_t)(b_panel * 2 + wc) * 131072 + (size_t)lane * 8;

    for (int kt = 0; kt < 32; ++kt) {
        bf16x8 A[2][4], Bf[2][4];
        const unsigned short* a0 = Ab + (size_t)kt * 8192;
        const unsigned short* b0 = Bb + (size_t)kt * 4096;
        #pragma unroll
        for (int s = 0; s < 2; ++s)
            #pragma unroll
            for (int m = 0; m < 4; ++m)
                A[s][m] = *reinterpret_cast<const bf16x8*>(a0 + s * 4096 + m * 512);
        #pragma unroll
        for (int s = 0; s < 2; ++s)
            #pragma unroll
            for (int n = 0; n < 4; ++n)
                Bf[s][n] = *reinterpret_cast<const bf16x8*>(b0 + s * 2048 + n * 512);
        #pragma unroll
        for (int m = 0; m < 4; ++m)
            #pragma unroll
            for (int n = 0; n < 4; ++n) {
                acc[m][n] = __builtin_amdgcn_mfma_f32_16x16x32_bf16(A[0][m], Bf[0][n], acc[m][n], 0, 0, 0);
                acc[m][n] = __builtin_amdgcn_mfma_f32_16x16x32_bf16(A[0][m], Bf[1][n], acc[m][n], 0, 0, 0);
                acc[m][n] = __builtin_amdgcn_mfma_f32_16x16x32_bf16(A[1][m], Bf[0][n], acc[m][n], 0, 0, 0);
            }
    }

    int spikes = 0;
    #pragma unroll
    for (int m = 0; m < 4; ++m) {
        const int h0l = hb0 + wr * 64 + m * 16 + g * 4;
        float4 bias = *reinterpret_cast<const float4*>(b1 + h0l);
        #pragma unroll
        for (int n = 0; n < 4; ++n) {
            const int b = bb0 + wc * 64 + n * 16 + l15;
            unsigned mk0 = lif_mask(acc[m][n][0] + bias.x);
            unsigned mk1 = lif_mask(acc[m][n][1] + bias.y);
            unsigned mk2 = lif_mask(acc[m][n][2] + bias.z);
            unsigned mk3 = lif_mask(acc[m][n][3] + bias.w);
            spikes += __popc(mk0) + __popc(mk1) + __popc(mk2) + __popc(mk3);
            *reinterpret_cast<uint2*>(M16 + (size_t)b * H_SZ + h0l) =
                make_uint2((mk0 & 0xffffu) | (mk1 << 16),
                           (mk2 & 0xffffu) | (mk3 << 16));
            *reinterpret_cast<unsigned int*>(M4 + (size_t)b * H_SZ + h0l) =
                (mk0 >> 16) | ((mk1 >> 16) << 8) | ((mk2 >> 16) << 16) | ((mk3 >> 16) << 24);
        }
    }
    #pragma unroll
    for (int off = 32; off > 0; off >>= 1)
        spikes += __shfl_down(spikes, off);
    if (lane == 0)
        atomicAdd(spike_count, (unsigned int)spikes);
}

// ---------------- K2: layer 2, LDS-free main loop ----------------
// launch_bounds(512,2): VGPR cap 256 — fits acc(80)+frags(32)+masks w/o spill,
// guards against module-context regalloc regressions (round-7: VGPR=76, +55% time).
#define TLV(b, c, t) sm_f32[(((b) * 32 + (c)) * 21) + (t)]
__global__ __launch_bounds__(512, 2) void k_layer2_mfma(
    const unsigned short* __restrict__ M16,
    const unsigned char* __restrict__ M4,
    const unsigned short* __restrict__ W2f,   // fragment-ordered
    const float* __restrict__ b2,
    float* __restrict__ out)
{
    __shared__ __align__(16) char smem[43008];
    float* sm_f32 = (float*)smem;

    const int tid  = threadIdx.x;
    const int w    = tid >> 6;
    const int tg   = w >> 1;          // t in [tg*5, tg*5+5)
    const int ch   = w & 1;           // cols [ch*64, ch*64+64)
    const int lane = tid & 63;
    const int l15  = lane & 15;
    const int g    = lane >> 4;
    const int b0   = blockIdx.x * 16;
    const int t0   = tg * 5;

    f32x4 acc[4][5];
    #pragma unroll
    for (int n = 0; n < 4; ++n)
        #pragma unroll
        for (int t = 0; t < 5; ++t)
            acc[n][t] = (f32x4){0.f, 0.f, 0.f, 0.f};

    const unsigned short* m16row = M16 + (size_t)(b0 + l15) * H_SZ;
    const unsigned char*  m4row  = M4  + (size_t)(b0 + l15) * H_SZ;
    const unsigned short* fbase  = W2f + (size_t)ch * 4096 + (size_t)lane * 8;

    for (int kt = 0; kt < 64; ++kt) {
        const int h0 = kt * 32;
        uint4 w16 = *reinterpret_cast<const uint4*>(m16row + h0 + g * 8);
        uint2 w4 = make_uint2(0u, 0u);
        if (tg == 3)
            w4 = *reinterpret_cast<const uint2*>(m4row + h0 + g * 8);

        bf16x8 bf[2][4];
        {
            const unsigned short* fk = fbase + (size_t)kt * 8192;
            #pragma unroll
            for (int s = 0; s < 2; ++s)
                #pragma unroll
                for (int nt = 0; nt < 4; ++nt)
                    bf[s][nt] = *reinterpret_cast<const bf16x8*>(fk + (s * 4 + nt) * 512);
        }

        #pragma unroll
        for (int tl_ = 0; tl_ < 5; ++tl_) {
            const int t = t0 + tl_;
            union { bf16x8 v; unsigned int u[4]; } A;
            if (t < 16) {
                A.u[0] = ((w16.x >> t) & 0x10001u) * 0x3F80u;
                A.u[1] = ((w16.y >> t) & 0x10001u) * 0x3F80u;
                A.u[2] = ((w16.z >> t) & 0x10001u) * 0x3F80u;
                A.u[3] = ((w16.w >> t) & 0x10001u) * 0x3F80u;
            } else {
                const int tt = t - 16;
                unsigned x0 = (w4.x >> tt)        & 0x101u;
                unsigned x1 = (w4.x >> (16 + tt)) & 0x101u;
                unsigned x2 = (w4.y >> tt)        & 0x101u;
                unsigned x3 = (w4.y >> (16 + tt)) & 0x101u;
                A.u[0] = ((x0 * 0x0101u) & 0x10001u) * 0x3F80u;
                A.u[1] = ((x1 * 0x0101u) & 0x10001u) * 0x3F80u;
                A.u[2] = ((x2 * 0x0101u) & 0x10001u) * 0x3F80u;
                A.u[3] = ((x3 * 0x0101u) & 0x10001u) * 0x3F80u;
            }
            #pragma unroll
            for (int nt = 0; nt < 4; ++nt) {
                acc[nt][tl_] = __builtin_amdgcn_mfma_f32_16x16x32_bf16(A.v, bf[0][nt], acc[nt][tl_], 0, 0, 0);
                acc[nt][tl_] = __builtin_amdgcn_mfma_f32_16x16x32_bf16(A.v, bf[1][nt], acc[nt][tl_], 0, 0, 0);
            }
        }
    }

    #pragma unroll
    for (int q = 0; q < 4; ++q) {
        __syncthreads();
        if (ch == (q >> 1)) {
            #pragma unroll
            for (int u = 0; u < 2; ++u) {
                const int nt = (q & 1) * 2 + u;
                const int cl = nt * 16 + l15 - (q & 1) * 32;   // 0..31
                #pragma unroll
                for (int tl_ = 0; tl_ < 5; ++tl_)
                    #pragma unroll
                    for (int j = 0; j < 4; ++j)
                        TLV(g * 4 + j, cl, t0 + tl_) = acc[nt][tl_][j];
            }
        }
        __syncthreads();
        {
            const int cl = tid & 31;
            const int bl = tid >> 5;
            const int c  = q * 32 + cl;
            const float bias = b2[c];
            float u2 = 0.0f; int cnt = 0;
            #pragma unroll
            for (int t = 0; t < T_STEPS; ++t) {
                float X = TLV(bl, cl, t) + bias;
                u2 = __fadd_rn(__fmul_rn(0.9f, u2), X);
                if (u2 >= 1.0f) { cnt++; u2 = 0.0f; }
            }
            out[(size_t)(b0 + bl) * C_SZ + c] = (float)cnt / 20.0f;
        }
    }
}

// ---------------- K3: mean_spikes = total / (B * T) ----------------
__global__ void k_finalize(const unsigned int* __restrict__ spike_count, float* __restrict__ out) {
    out[(size_t)B_SZ * C_SZ] = (float)(*spike_count) / (float)((size_t)B_SZ * T_STEPS);
}

extern "C" void kernel_launch(void* const* d_in, const int* in_sizes, int n_in,
                              void* d_out, int out_size, void* d_ws, size_t ws_size,
                              hipStream_t stream) {
    const float* x  = (const float*)d_in[0];
    const float* W1 = (const float*)d_in[1];
    const float* b1 = (const float*)d_in[2];
    const float* W2 = (const float*)d_in[3];
    const float* b2 = (const float*)d_in[4];
    float* out = (float*)d_out;

    char* ws = (char*)d_ws;
    const size_t m16_b = (size_t)B_SZ * H_SZ * 2;        // 67.1 MB
    const size_t m4_b  = (size_t)B_SZ * H_SZ;            // 33.6 MB
    const size_t w1s_b = (size_t)2 * H_SZ * D_SZ * 2;    // 8.4 MB
    const size_t w2p_b = (size_t)2 * C_SZ * H_SZ * 2;    // 1.05 MB
    const size_t xf_b  = (size_t)2 * B_SZ * D_SZ * 2;    // 67.1 MB
    const size_t w1f_b = w1s_b;                          // 8.4 MB

    size_t off = 0;
    unsigned short* M16 = (unsigned short*)(ws + off); off += m16_b;
    unsigned char*  M4  = (unsigned char*)(ws + off);  off += m4_b;
    unsigned short* w1s = (unsigned short*)(ws + off); off += w1s_b;
    unsigned short* W2p = (unsigned short*)(ws + off); off += w2p_b;
    unsigned short* W2f = (unsigned short*)(ws + off); off += w2p_b;
    unsigned int* counter = (unsigned int*)(ws + off); off += 256;
    unsigned short* xf  = (unsigned short*)(ws + off); off += xf_b;
    unsigned short* w1f = (unsigned short*)(ws + off); off += w1f_b;

    hipMemsetAsync(counter, 0, sizeof(unsigned int), stream);

    k_split2<<<(H_SZ * D_SZ) / 1024, 256, 0, stream>>>(W1, w1s, H_SZ * D_SZ);
    k_split2<<<(C_SZ * H_SZ) / 1024, 256, 0, stream>>>(W2, W2p, C_SZ * H_SZ);
    k_w2frag<<<256, 256, 0, stream>>>(W2p, W2f);
    k_w1frag<<<2048, 256, 0, stream>>>(w1s, w1f);
    k_xfrag<<<8192, 256, 0, stream>>>(x, xf);

    k_gemm1_frag<<<2048, 256, 0, stream>>>(xf, w1f, b1, M16, M4, counter);

    k_layer2_mfma<<<B_SZ / 16, 512, 0, stream>>>(M16, M4, W2f, b2, out);

    k_finalize<<<1, 1, 0, stream>>>(counter, out);
}

// Round 9
// 522.640 us; speedup vs baseline: 1.0954x; 1.0954x over previous
//
#include <hip/hip_runtime.h>
#include <hip/hip_bf16.h>

#define B_SZ 16384
#define D_SZ 1024
#define H_SZ 2048
#define C_SZ 128
#define T_STEPS 20

typedef __attribute__((ext_vector_type(4))) float f32x4;
typedef __attribute__((ext_vector_type(8))) short bf16x8;

__device__ __forceinline__ unsigned int lif_mask(float i1) {
    float u = 0.0f;
    unsigned int m = 0;
    #pragma unroll
    for (int t = 0; t < T_STEPS; ++t) {
        u = __fadd_rn(__fmul_rn(0.9f, u), i1);   // match np: separate mul, add
        if (u >= 1.0f) { m |= (1u << t); u = 0.0f; }
    }
    return m;
}

// ---------------- generic fp32 -> 2 bf16 planes splitter (RNE hi, RNE mid) ----------
__global__ void k_split2(const float* __restrict__ src, unsigned short* __restrict__ dst, int n) {
    int i = blockIdx.x * blockDim.x + threadIdx.x;   // float4 index
    float4 v = reinterpret_cast<const float4*>(src)[i];
    float f[4] = {v.x, v.y, v.z, v.w};
    unsigned short h[4], m[4];
    #pragma unroll
    for (int j = 0; j < 4; ++j) {
        __hip_bfloat16 hb = __float2bfloat16(f[j]);
        h[j] = __bfloat16_as_ushort(hb);
        m[j] = __bfloat16_as_ushort(__float2bfloat16(f[j] - __bfloat162float(hb)));
    }
    reinterpret_cast<ushort4*>(dst)[i] = make_ushort4(h[0], h[1], h[2], h[3]);
    reinterpret_cast<ushort4*>(dst + n)[i] = make_ushort4(m[0], m[1], m[2], m[3]);
}

// ---------------- pre-permute W2 planes into MFMA fragment order (K2, 8-nt) ----------
// dst u16 layout: [kt(64)][s(2)][nt(8)][lane(64)][8]
// value = W2p[s][c = nt*16 + (lane&15)][h = kt*32 + (lane>>4)*8 .. +7]
__global__ void k_w2frag8(const unsigned short* __restrict__ W2p, unsigned short* __restrict__ W2f) {
    int idx = blockIdx.x * blockDim.x + threadIdx.x;   // 0..65535
    int lane = idx & 63;
    int nt   = (idx >> 6) & 7;
    int s    = (idx >> 9) & 1;
    int kt   = idx >> 10;
    int c = nt * 16 + (lane & 15);
    int h = kt * 32 + (lane >> 4) * 8;
    uint4 v = *reinterpret_cast<const uint4*>(W2p + ((size_t)s * C_SZ + c) * H_SZ + h);
    *reinterpret_cast<uint4*>(W2f + (size_t)idx * 8) = v;
}

// ---------------- pre-permute W1 planes into MFMA fragment order (K1) ----------------
// dst u16 layout: [p(16)][kt(32)][s(2)][m(8)][lane(64)][8]
// value = w1s[s][h = p*128 + m*16 + (lane&15)][k = kt*32 + (lane>>4)*8 .. +7]
__global__ void k_w1frag(const unsigned short* __restrict__ w1s, unsigned short* __restrict__ w1f) {
    int idx = blockIdx.x * blockDim.x + threadIdx.x;   // 0..524287
    int lane = idx & 63;
    int m    = (idx >> 6) & 7;
    int s    = (idx >> 9) & 1;
    int kt   = (idx >> 10) & 31;
    int p    = idx >> 15;
    int h = p * 128 + m * 16 + (lane & 15);
    int k = kt * 32 + (lane >> 4) * 8;
    uint4 v = *reinterpret_cast<const uint4*>(w1s + ((size_t)s * H_SZ + h) * D_SZ + k);
    *reinterpret_cast<uint4*>(w1f + (size_t)idx * 8) = v;
}

// ---------------- fused split + frag-permute of x -----------------------------------
// dst u16 layout: [bg(256)][kt(32)][s(2)][nt(4)][lane(64)][8]
// value = splitplane_s( x[b = bg*64 + nt*16 + (lane&15)][k = kt*32 + (lane>>4)*8 .. +7] )
__global__ void k_xfrag(const float* __restrict__ x, unsigned short* __restrict__ xf) {
    int idx = blockIdx.x * blockDim.x + threadIdx.x;   // 0..2097151
    int lane = idx & 63;
    int nt   = (idx >> 6) & 3;
    int kt   = (idx >> 8) & 31;
    int bg   = idx >> 13;
    int b = bg * 64 + nt * 16 + (lane & 15);
    int k = kt * 32 + (lane >> 4) * 8;
    const float* src = x + (size_t)b * D_SZ + k;
    float4 v0 = *reinterpret_cast<const float4*>(src);
    float4 v1 = *reinterpret_cast<const float4*>(src + 4);
    float f[8] = {v0.x, v0.y, v0.z, v0.w, v1.x, v1.y, v1.z, v1.w};
    unsigned short h[8], m[8];
    #pragma unroll
    for (int j = 0; j < 8; ++j) {
        __hip_bfloat16 hb = __float2bfloat16(f[j]);
        h[j] = __bfloat16_as_ushort(hb);
        m[j] = __bfloat16_as_ushort(__float2bfloat16(f[j] - __bfloat162float(hb)));
    }
    size_t base = (((size_t)(bg * 32 + kt) * 8) + nt) * 512 + (size_t)lane * 8;
    *reinterpret_cast<ushort4*>(xf + base)         = make_ushort4(h[0], h[1], h[2], h[3]);
    *reinterpret_cast<ushort4*>(xf + base + 4)     = make_ushort4(h[4], h[5], h[6], h[7]);
    *reinterpret_cast<ushort4*>(xf + base + 2048)  = make_ushort4(m[0], m[1], m[2], m[3]);
    *reinterpret_cast<ushort4*>(xf + base + 2052)  = make_ushort4(m[4], m[5], m[6], m[7]);
}

// ---------------- K1: LDS-free, barrier-free frag-GEMM + fused LIF -------------------
// (round-7 kernel, unchanged) Grid 2048 x 256 thr (4 waves, 64x64 out each).
__global__ __launch_bounds__(256, 2) void k_gemm1_frag(
    const unsigned short* __restrict__ xf,    // fragment-ordered x planes
    const unsigned short* __restrict__ w1f,   // fragment-ordered W1 planes
    const float* __restrict__ b1,
    unsigned short* __restrict__ M16,
    unsigned char* __restrict__ M4,
    unsigned int* __restrict__ spike_count)
{
    const int tid  = threadIdx.x;
    const int wv   = tid >> 6;
    const int lane = tid & 63;
    const int l15  = lane & 15;
    const int g    = lane >> 4;
    const int wr   = wv >> 1;
    const int wc   = wv & 1;

    const int wg    = blockIdx.x;
    const int xcd   = wg & 7;
    const int local = wg >> 3;
    const int sc    = local >> 4;
    const int sl    = local & 15;
    const int b_panel = xcd * 16 + (sc >> 2) * 4 + (sl >> 2);
    const int h_idx   = (sc & 3) * 4 + (sl & 3);
    const int hb0 = h_idx * 128;
    const int bb0 = b_panel * 128;

    f32x4 acc[4][4];
    #pragma unroll
    for (int i = 0; i < 4; ++i)
        #pragma unroll
        for (int j = 0; j < 4; ++j)
            acc[i][j] = (f32x4){0.f, 0.f, 0.f, 0.f};

    // A: [p][kt][s][m][lane*8]; strides (u16): m 512, s 4096, kt 8192, p 262144
    const unsigned short* Ab = w1f + (size_t)h_idx * 262144 + (size_t)wr * 2048 + (size_t)lane * 8;
    // B: [bg][kt][s][nt][lane*8]; strides (u16): nt 512, s 2048, kt 4096, bg 131072
    const unsigned short* Bb = xf + (size_t)(b_panel * 2 + wc) * 131072 + (size_t)lane * 8;

    for (int kt = 0; kt < 32; ++kt) {
        bf16x8 A[2][4], Bf[2][4];
        const unsigned short* a0 = Ab + (size_t)kt * 8192;
        const unsigned short* b0 = Bb + (size_t)kt * 4096;
        #pragma unroll
        for (int s = 0; s < 2; ++s)
            #pragma unroll
            for (int m = 0; m < 4; ++m)
                A[s][m] = *reinterpret_cast<const bf16x8*>(a0 + s * 4096 + m * 512);
        #pragma unroll
        for (int s = 0; s < 2; ++s)
            #pragma unroll
            for (int n = 0; n < 4; ++n)
                Bf[s][n] = *reinterpret_cast<const bf16x8*>(b0 + s * 2048 + n * 512);
        #pragma unroll
        for (int m = 0; m < 4; ++m)
            #pragma unroll
            for (int n = 0; n < 4; ++n) {
                acc[m][n] = __builtin_amdgcn_mfma_f32_16x16x32_bf16(A[0][m], Bf[0][n], acc[m][n], 0, 0, 0);
                acc[m][n] = __builtin_amdgcn_mfma_f32_16x16x32_bf16(A[0][m], Bf[1][n], acc[m][n], 0, 0, 0);
                acc[m][n] = __builtin_amdgcn_mfma_f32_16x16x32_bf16(A[1][m], Bf[0][n], acc[m][n], 0, 0, 0);
            }
    }

    int spikes = 0;
    #pragma unroll
    for (int m = 0; m < 4; ++m) {
        const int h0l = hb0 + wr * 64 + m * 16 + g * 4;
        float4 bias = *reinterpret_cast<const float4*>(b1 + h0l);
        #pragma unroll
        for (int n = 0; n < 4; ++n) {
            const int b = bb0 + wc * 64 + n * 16 + l15;
            unsigned mk0 = lif_mask(acc[m][n][0] + bias.x);
            unsigned mk1 = lif_mask(acc[m][n][1] + bias.y);
            unsigned mk2 = lif_mask(acc[m][n][2] + bias.z);
            unsigned mk3 = lif_mask(acc[m][n][3] + bias.w);
            spikes += __popc(mk0) + __popc(mk1) + __popc(mk2) + __popc(mk3);
            *reinterpret_cast<uint2*>(M16 + (size_t)b * H_SZ + h0l) =
                make_uint2((mk0 & 0xffffu) | (mk1 << 16),
                           (mk2 & 0xffffu) | (mk3 << 16));
            *reinterpret_cast<unsigned int*>(M4 + (size_t)b * H_SZ + h0l) =
                (mk0 >> 16) | ((mk1 >> 16) << 8) | ((mk2 >> 16) << 16) | ((mk3 >> 16) << 24);
        }
    }
    #pragma unroll
    for (int off = 32; off > 0; off >>= 1)
        spikes += __shfl_down(spikes, off);
    if (lane == 0)
        atomicAdd(spike_count, (unsigned int)spikes);
}

// ---------------- K2: layer 2, LDS-free main loop, 4 waves x 8 n-tiles ----------------
// 256 thr = 4 waves; wave tg owns 5 timesteps x ALL 128 cols, 16 b-rows/block.
// A-expand (12 VALU / K=32 frag) now feeds 16 MFMAs (was 8) -> VALU:MFMA ~0.4:1.
// acc[8][5] = 160 AGPRs; Bf loaded per-s (32 VGPRs live). Accumulation order
// (s0 then s1 per 32-h chunk) identical to previous version -> bit-identical output.
__global__ __launch_bounds__(256, 2) void k_layer2_mfma(
    const unsigned short* __restrict__ M16,
    const unsigned char* __restrict__ M4,
    const unsigned short* __restrict__ W2f,   // frag-ordered [kt][s][nt8][lane][8]
    const float* __restrict__ b2,
    float* __restrict__ out)
{
    __shared__ __align__(16) float smem[5700];   // 16b x 16c (pad 17) x 21t
    const int tid  = threadIdx.x;
    const int tg   = tid >> 6;        // wave = t-group: t in [tg*5, tg*5+5)
    const int lane = tid & 63;
    const int l15  = lane & 15;
    const int g    = lane >> 4;
    const int b0   = blockIdx.x * 16;
    const int t0   = tg * 5;

    f32x4 acc[8][5];
    #pragma unroll
    for (int n = 0; n < 8; ++n)
        #pragma unroll
        for (int t = 0; t < 5; ++t)
            acc[n][t] = (f32x4){0.f, 0.f, 0.f, 0.f};

    const unsigned short* m16row = M16 + (size_t)(b0 + l15) * H_SZ + g * 8;
    const unsigned char*  m4row  = M4  + (size_t)(b0 + l15) * H_SZ + g * 8;
    const unsigned short* fbase  = W2f + (size_t)lane * 8;

    for (int kt = 0; kt < 64; ++kt) {
        uint4 w16 = *reinterpret_cast<const uint4*>(m16row + kt * 32);
        uint2 w4 = make_uint2(0u, 0u);
        if (tg == 3)
            w4 = *reinterpret_cast<const uint2*>(m4row + kt * 32);

        // build A fragments for this wave's 5 timesteps (K=32 each)
        union { bf16x8 v; unsigned int u[4]; } A[5];
        #pragma unroll
        for (int tl = 0; tl < 5; ++tl) {
            const int t = t0 + tl;
            if (t < 16) {
                A[tl].u[0] = ((w16.x >> t) & 0x10001u) * 0x3F80u;
                A[tl].u[1] = ((w16.y >> t) & 0x10001u) * 0x3F80u;
                A[tl].u[2] = ((w16.z >> t) & 0x10001u) * 0x3F80u;
                A[tl].u[3] = ((w16.w >> t) & 0x10001u) * 0x3F80u;
            } else {
                const int tt = t - 16;
                unsigned x0 = (w4.x >> tt)        & 0x101u;
                unsigned x1 = (w4.x >> (16 + tt)) & 0x101u;
                unsigned x2 = (w4.y >> tt)        & 0x101u;
                unsigned x3 = (w4.y >> (16 + tt)) & 0x101u;
                A[tl].u[0] = ((x0 * 0x0101u) & 0x10001u) * 0x3F80u;
                A[tl].u[1] = ((x1 * 0x0101u) & 0x10001u) * 0x3F80u;
                A[tl].u[2] = ((x2 * 0x0101u) & 0x10001u) * 0x3F80u;
                A[tl].u[3] = ((x3 * 0x0101u) & 0x10001u) * 0x3F80u;
            }
        }

        const unsigned short* fk = fbase + (size_t)kt * 8192;
        #pragma unroll
        for (int s = 0; s < 2; ++s) {
            bf16x8 Bf[8];
            #pragma unroll
            for (int nt = 0; nt < 8; ++nt)
                Bf[nt] = *reinterpret_cast<const bf16x8*>(fk + s * 4096 + nt * 512);
            #pragma unroll
            for (int tl = 0; tl < 5; ++tl)
                #pragma unroll
                for (int nt = 0; nt < 8; ++nt)
                    acc[nt][tl] = __builtin_amdgcn_mfma_f32_16x16x32_bf16(
                        A[tl].v, Bf[nt], acc[nt][tl], 0, 0, 0);
        }
    }

    // epilogue: 8 chunks of 16 cols; transpose through LDS, then LIF per (b,c)
    #pragma unroll
    for (int q = 0; q < 8; ++q) {
        __syncthreads();
        #pragma unroll
        for (int tl = 0; tl < 5; ++tl)
            #pragma unroll
            for (int j = 0; j < 4; ++j)
                smem[((g * 4 + j) * 17 + l15) * 21 + (t0 + tl)] = acc[q][tl][j];
        __syncthreads();
        {
            const int bl  = tid >> 4;     // 0..15
            const int c16 = tid & 15;
            const int c   = q * 16 + c16;
            const float bias = b2[c];
            float u2 = 0.0f; int cnt = 0;
            #pragma unroll
            for (int t = 0; t < T_STEPS; ++t) {
                float X = smem[(bl * 17 + c16) * 21 + t] + bias;
                u2 = __fadd_rn(__fmul_rn(0.9f, u2), X);
                if (u2 >= 1.0f) { cnt++; u2 = 0.0f; }
            }
            out[(size_t)(b0 + bl) * C_SZ + c] = (float)cnt / 20.0f;
        }
    }
}

// ---------------- K3: mean_spikes = total / (B * T) ----------------
__global__ void k_finalize(const unsigned int* __restrict__ spike_count, float* __restrict__ out) {
    out[(size_t)B_SZ * C_SZ] = (float)(*spike_count) / (float)((size_t)B_SZ * T_STEPS);
}

extern "C" void kernel_launch(void* const* d_in, const int* in_sizes, int n_in,
                              void* d_out, int out_size, void* d_ws, size_t ws_size,
                              hipStream_t stream) {
    const float* x  = (const float*)d_in[0];
    const float* W1 = (const float*)d_in[1];
    const float* b1 = (const float*)d_in[2];
    const float* W2 = (const float*)d_in[3];
    const float* b2 = (const float*)d_in[4];
    float* out = (float*)d_out;

    char* ws = (char*)d_ws;
    const size_t m16_b = (size_t)B_SZ * H_SZ * 2;        // 67.1 MB
    const size_t m4_b  = (size_t)B_SZ * H_SZ;            // 33.6 MB
    const size_t w1s_b = (size_t)2 * H_SZ * D_SZ * 2;    // 8.4 MB
    const size_t w2p_b = (size_t)2 * C_SZ * H_SZ * 2;    // 1.05 MB
    const size_t xf_b  = (size_t)2 * B_SZ * D_SZ * 2;    // 67.1 MB
    const size_t w1f_b = w1s_b;                          // 8.4 MB

    size_t off = 0;
    unsigned short* M16 = (unsigned short*)(ws + off); off += m16_b;
    unsigned char*  M4  = (unsigned char*)(ws + off);  off += m4_b;
    unsigned short* w1s = (unsigned short*)(ws + off); off += w1s_b;
    unsigned short* W2p = (unsigned short*)(ws + off); off += w2p_b;
    unsigned short* W2f = (unsigned short*)(ws + off); off += w2p_b;
    unsigned int* counter = (unsigned int*)(ws + off); off += 256;
    unsigned short* xf  = (unsigned short*)(ws + off); off += xf_b;
    unsigned short* w1f = (unsigned short*)(ws + off); off += w1f_b;

    hipMemsetAsync(counter, 0, sizeof(unsigned int), stream);

    k_split2<<<(H_SZ * D_SZ) / 1024, 256, 0, stream>>>(W1, w1s, H_SZ * D_SZ);
    k_split2<<<(C_SZ * H_SZ) / 1024, 256, 0, stream>>>(W2, W2p, C_SZ * H_SZ);
    k_w2frag8<<<256, 256, 0, stream>>>(W2p, W2f);
    k_w1frag<<<2048, 256, 0, stream>>>(w1s, w1f);
    k_xfrag<<<8192, 256, 0, stream>>>(x, xf);

    k_gemm1_frag<<<2048, 256, 0, stream>>>(xf, w1f, b1, M16, M4, counter);

    k_layer2_mfma<<<B_SZ / 16, 256, 0, stream>>>(M16, M4, W2f, b2, out);

    k_finalize<<<1, 1, 0, stream>>>(counter, out);
}